// Round 17
// baseline (157.724 us; speedup 1.0000x reference)
//
#include <hip/hip_runtime.h>
#include <stdint.h>

typedef unsigned short u16;
typedef unsigned int u32;
typedef __attribute__((ext_vector_type(4))) float f32x4;
typedef __attribute__((ext_vector_type(8))) short short8;
typedef __attribute__((ext_vector_type(8))) _Float16 f16x8;

#define H 8
#define LSEQ 2048
#define E 1024
#define DK 512
#define DVH 128
#define DKH 64
#define NCHUNK 32
#define MROWS 8192
#define LN_EPS 1e-5f

#define AS1 __attribute__((address_space(1)))
#define AS3 __attribute__((address_space(3)))

static __device__ __forceinline__ float bf2f(u16 u) {
    union { float f; u32 i; } v; v.i = ((u32)u) << 16; return v.f;
}
static __device__ __forceinline__ u16 f2bf(float f) {
    union { float f; u32 i; } v; v.f = f;
    u32 r = v.i + 0x7FFFu + ((v.i >> 16) & 1u);
    return (u16)(r >> 16);
}

// ---------------------------------------------------------------- conv+silu
__global__ __launch_bounds__(256) void k_conv(const float* __restrict__ x,
                                              const float* __restrict__ cw,
                                              u16* __restrict__ xc) {
    const int l0 = blockIdx.x * 64;
    const int c  = blockIdx.y * 256 + threadIdx.x;
    const int b  = blockIdx.z;
    const f32x4 w = *(const f32x4*)(cw + c * 4);
    const float* base = x + (size_t)b * LSEQ * E + c;
    u16* ob = xc + (size_t)b * LSEQ * E + c;
    float x3 = (l0 >= 3) ? base[(size_t)(l0 - 3) * E] : 0.f;
    float x2 = (l0 >= 2) ? base[(size_t)(l0 - 2) * E] : 0.f;
    float x1 = (l0 >= 1) ? base[(size_t)(l0 - 1) * E] : 0.f;
#pragma unroll 8
    for (int r = 0; r < 64; r++) {
        const float x0 = base[(size_t)(l0 + r) * E];
        float a = x3 * w[0];
        a = fmaf(x2, w[1], a);
        a = fmaf(x1, w[2], a);
        a = fmaf(x0, w[3], a);
        const float s = a / (1.f + __expf(-a));
        ob[(size_t)(l0 + r) * E] = f2bf(s);
        x3 = x2; x2 = x1; x1 = x0;
    }
}

// ------------------------------------------- fused weight transpose + cast
__global__ __launch_bounds__(256) void k_transpose_all(const float* __restrict__ wq,
                                                       const float* __restrict__ wkg,
                                                       const float* __restrict__ wv,
                                                       const float* __restrict__ wg,
                                                       const float* __restrict__ wout,
                                                       u16* __restrict__ wcat,
                                                       u16* __restrict__ woutT) {
    __shared__ float tile[32][33];
    const int z = blockIdx.z;
    const float* src; u16* dst; int Ncols;
    if (z == 0)      { src = wq;   dst = wcat;                        Ncols = 512; }
    else if (z == 1) { src = wkg;  dst = wcat + (size_t)512 * 1024;   Ncols = 512; }
    else if (z == 2) { src = wv;   dst = wcat + (size_t)1024 * 1024;  Ncols = 1024; }
    else if (z == 3) { src = wg;   dst = wcat + (size_t)2048 * 1024;  Ncols = 1024; }
    else             { src = wout; dst = woutT;                       Ncols = 1024; }
    const int n0 = blockIdx.x * 32, k0 = blockIdx.y * 32;
    if (n0 >= Ncols) return;
    const int K = 1024;
    const int tx = threadIdx.x & 31, ty = threadIdx.x >> 5;   // ty 0..7
#pragma unroll
    for (int p = 0; p < 4; p++) {
        const int r = p * 8 + ty;
        tile[r][tx] = src[(size_t)(k0 + r) * Ncols + n0 + tx];
    }
    __syncthreads();
#pragma unroll
    for (int p = 0; p < 4; p++) {
        const int rn = p * 8 + ty;
        dst[(size_t)(n0 + rn) * K + k0 + tx] = f2bf(tile[tx][rn]);
    }
}

// -------------------------------------------------------- GEMM0 (projection)
// Round-8 proven structure (best measured: ~69 us): 128x384 tile, BK=32
// halves, 4-slot ring (32 KB/slot, 128 KB). 8 waves 2Mx4N (64x96 each).
// Counted vmcnt(8/4/0), stage 3 ahead, no forced lgkmcnt.
__global__ __launch_bounds__(512, 1) void k_gemm0(const u16* __restrict__ A,
                                                  const u16* __restrict__ Bt,
                                                  u16* __restrict__ oQ, u16* __restrict__ oKG,
                                                  u16* __restrict__ oV, u16* __restrict__ oSG,
                                                  const float* __restrict__ bg) {
    const int K = 1024;
    __shared__ __align__(16) u16 smem[4][16384];
    const int tid = threadIdx.x;
    const int lane = tid & 63, wv = tid >> 6;      // 8 waves
    const int wm = wv >> 2, wn = wv & 3;           // 2M x 4N, 64x96 per wave

    const int id = blockIdx.x;                     // 0..511
    const int local = id >> 3;                     // 0..63
    const int bx = ((id & 7) << 3) | (local & 7);  // 0..63
    const int by = local >> 3;                     // 0..7

    const size_t rowBase = (size_t)bx * 128;
    const size_t colBase = (size_t)by * 384;

    const int rowIn = lane >> 2;                   // 0..15
    const int uIn = lane & 3;

    auto stageA = [&](int hh) {
        u16* slotA = &smem[hh & 3][0];
        const u16* g = A + rowBase * K + hh * 32;
        const int row = wv * 16 + rowIn;           // 0..127
        const int sg = uIn ^ ((row >> 1) & 3);
        __builtin_amdgcn_global_load_lds(
            (const AS1 void*)(g + (size_t)row * K + sg * 8),
            (AS3 void*)(slotA + wv * 512), 16, 0, 0);
    };
    auto stageB = [&](int hh) {
        u16* slotB = &smem[hh & 3][4096];
        const u16* g = Bt + colBase * K + hh * 32;
#pragma unroll
        for (int i = 0; i < 3; i++) {
            const int row = i * 128 + wv * 16 + rowIn;   // 0..383
            const int sg = uIn ^ ((row >> 1) & 3);
            __builtin_amdgcn_global_load_lds(
                (const AS1 void*)(g + (size_t)row * K + sg * 8),
                (AS3 void*)(slotB + i * 4096 + wv * 512), 16, 0, 0);
        }
    };

    f32x4 acc[4][6];
#pragma unroll
    for (int m = 0; m < 4; m++)
#pragma unroll
        for (int n = 0; n < 6; n++) acc[m][n] = (f32x4){0.f, 0.f, 0.f, 0.f};

    const int rsub = lane & 15;
    const int cgl = lane >> 4;

    stageA(0); stageB(0);
    stageA(1); stageB(1);
    stageA(2); stageB(2);

    const int NT2 = K >> 5;   // 32 halves
    for (int h = 0; h < NT2; h++) {
        const int rem = NT2 - 1 - h;
        if (rem >= 2)      asm volatile("s_waitcnt vmcnt(8)" ::: "memory");
        else if (rem == 1) asm volatile("s_waitcnt vmcnt(4)" ::: "memory");
        else               asm volatile("s_waitcnt vmcnt(0)" ::: "memory");
        asm volatile("s_barrier" ::: "memory");
        const u16* As = &smem[h & 3][0];
        const u16* Bs = As + 4096;
        short8 af[4], bfr[6];
#pragma unroll
        for (int mi = 0; mi < 4; mi++) {
            const int row = wm * 64 + mi * 16 + rsub;
            const int g = cgl ^ ((row >> 1) & 3);
            af[mi] = *(const short8*)(As + row * 32 + g * 8);
        }
#pragma unroll
        for (int ni = 0; ni < 6; ni++) {
            const int row = wn * 96 + ni * 16 + rsub;
            const int g = cgl ^ ((row >> 1) & 3);
            bfr[ni] = *(const short8*)(Bs + row * 32 + g * 8);
        }
        if (h + 3 < NT2) { stageA(h + 3); stageB(h + 3); }   // -> slot (h-1)&3
        __builtin_amdgcn_s_setprio(1);
#pragma unroll
        for (int mi = 0; mi < 4; mi++)
#pragma unroll
            for (int ni = 0; ni < 6; ni++)
                acc[mi][ni] = __builtin_amdgcn_mfma_f32_16x16x32_bf16(af[mi], bfr[ni], acc[mi][ni], 0, 0, 0);
        __builtin_amdgcn_s_setprio(0);
    }

    // ---- epilogue: silu on g-cols, repack via LDS, coalesced stores
    const int r0 = (lane >> 4) * 4;
    u16* lds = &smem[0][0];            // 128x384 u16 = 96 KB
    __syncthreads();
#pragma unroll
    for (int ni = 0; ni < 6; ni++) {
        const int colg = (int)colBase + wn * 96 + ni * 16 + rsub;
        const bool isSG = (colg >= 2048);
        const float bgv = isSG ? bg[colg - 2048] : 0.f;
#pragma unroll
        for (int mi = 0; mi < 4; mi++) {
            const int lcol = wn * 96 + ni * 16 + rsub;
#pragma unroll
            for (int r = 0; r < 4; r++) {
                const int lrow = wm * 64 + mi * 16 + r0 + r;
                float val = acc[mi][ni][r];
                if (isSG) { const float y = val + bgv; val = y / (1.f + __expf(-y)); }
                lds[lrow * 384 + lcol] = f2bf(val);
            }
        }
    }
    __syncthreads();
    if (lane < 48) {
        const int col = (int)colBase + lane * 8;
        u16* seg; int stride; int c0;
        if (col < 512)       { seg = oQ;  stride = 512;  c0 = col; }
        else if (col < 1024) { seg = oKG; stride = 512;  c0 = col - 512; }
        else if (col < 2048) { seg = oV;  stride = 1024; c0 = col - 1024; }
        else                 { seg = oSG; stride = 1024; c0 = col - 2048; }
#pragma unroll
        for (int rr = 0; rr < 16; rr++) {
            const int lrow = wv * 16 + rr;
            const uint4 vv = *(const uint4*)(lds + lrow * 384 + lane * 8);
            *(uint4*)(seg + (rowBase + lrow) * (size_t)stride + c0) = vv;
        }
    }
}

// ------------------------------------------------------------ GEMM1 (output)
__global__ __launch_bounds__(512, 1) void k_gemm1(const u16* __restrict__ A,
                                                  const u16* __restrict__ Bt,
                                                  float* __restrict__ oF) {
    const int K = 1024, N = 1024;
    __shared__ __align__(16) u16 smem[4][12288];   // 96 KB
    const int tid = threadIdx.x;
    const int lane = tid & 63, wv = tid >> 6;
    const int wm = wv >> 1, wn = wv & 1;

    const int id = blockIdx.y * gridDim.x + blockIdx.x;
    const int bx = ((id & 7) << 2) | ((id >> 3) & 3);
    const int by = id >> 5;

    const size_t rowBase = (size_t)bx * 256;
    const size_t colBase = (size_t)by * 128;

    auto stageA = [&](int hh) {
        u16* slotA = &smem[hh & 3][0];
        const u16* g = A + rowBase * K + hh * 32;
#pragma unroll
        for (int i = 0; i < 2; i++) {
            const int r = i * 128 + wv * 16 + (lane >> 2);
            const int sg = (lane & 3) ^ ((r >> 1) & 3);
            __builtin_amdgcn_global_load_lds(
                (const AS1 void*)(g + (size_t)r * K + sg * 8),
                (AS3 void*)(slotA + i * 4096 + wv * 512), 16, 0, 0);
        }
    };
    auto stageB = [&](int hh) {
        u16* slotB = &smem[hh & 3][8192];
        const u16* g = Bt + colBase * K + hh * 32;
        const int r = wv * 16 + (lane >> 2);
        const int sg = (lane & 3) ^ ((r >> 1) & 3);
        __builtin_amdgcn_global_load_lds(
            (const AS1 void*)(g + (size_t)r * K + sg * 8),
            (AS3 void*)(slotB + wv * 512), 16, 0, 0);
    };

    f32x4 acc[4][4];
#pragma unroll
    for (int m = 0; m < 4; m++)
#pragma unroll
        for (int n = 0; n < 4; n++) acc[m][n] = (f32x4){0.f, 0.f, 0.f, 0.f};

    const int rsub = lane & 15;
    const int cgl = lane >> 4;

    stageA(0); stageB(0);
    stageA(1); stageB(1);
    stageA(2); stageB(2);

    const int NT2 = K >> 5;
    for (int h = 0; h < NT2; h++) {
        const int rem = NT2 - 1 - h;
        if (rem >= 2)      asm volatile("s_waitcnt vmcnt(6)" ::: "memory");
        else if (rem == 1) asm volatile("s_waitcnt vmcnt(3)" ::: "memory");
        else               asm volatile("s_waitcnt vmcnt(0)" ::: "memory");
        asm volatile("s_barrier" ::: "memory");
        const u16* As = &smem[h & 3][0];
        const u16* Bs = As + 8192;
        short8 af[4], bfr[4];
#pragma unroll
        for (int mi = 0; mi < 4; mi++) {
            const int row = wm * 64 + mi * 16 + rsub;
            const int g = cgl ^ ((row >> 1) & 3);
            af[mi] = *(const short8*)(As + row * 32 + g * 8);
        }
#pragma unroll
        for (int ni = 0; ni < 4; ni++) {
            const int row = wn * 64 + ni * 16 + rsub;
            const int g = cgl ^ ((row >> 1) & 3);
            bfr[ni] = *(const short8*)(Bs + row * 32 + g * 8);
        }
        if (h + 3 < NT2) { stageA(h + 3); stageB(h + 3); }
        __builtin_amdgcn_s_setprio(1);
#pragma unroll
        for (int mi = 0; mi < 4; mi++)
#pragma unroll
            for (int ni = 0; ni < 4; ni++)
                acc[mi][ni] = __builtin_amdgcn_mfma_f32_16x16x32_bf16(af[mi], bfr[ni], acc[mi][ni], 0, 0, 0);
        __builtin_amdgcn_s_setprio(0);
    }

    // ---- epilogue: two 128-row passes via padded f32 LDS [128][132]
    const int r0 = (lane >> 4) * 4;
    float* lf = (float*)&smem[0][0];   // 128*132*4 = 67584 B <= 96 KB
#pragma unroll
    for (int p = 0; p < 2; p++) {
        __syncthreads();
        if ((wm >> 1) == p) {
            const int wml = wm & 1;
#pragma unroll
            for (int mi = 0; mi < 4; mi++)
#pragma unroll
                for (int ni = 0; ni < 4; ni++) {
                    const int lcol = wn * 64 + ni * 16 + rsub;
#pragma unroll
                    for (int r = 0; r < 4; r++) {
                        const int lrow = wml * 64 + mi * 16 + r0 + r;
                        lf[lrow * 132 + lcol] = acc[mi][ni][r];
                    }
                }
        }
        __syncthreads();
#pragma unroll
        for (int i = 0; i < 8; i++) {
            const int unit = i * 512 + tid;
            const int row = unit >> 5, u = unit & 31;
            const f32x4 vv = *(const f32x4*)(lf + row * 132 + u * 4);
            *(f32x4*)(oF + (rowBase + p * 128 + row) * (size_t)N + colBase + u * 4) = vv;
        }
    }
}

// ------------------------------------------------------- GLA phase 1 (intra)
__global__ __launch_bounds__(256) void k_gla1(const u16* __restrict__ q,
                                              const u16* __restrict__ kg,
                                              const u16* __restrict__ v,
                                              const float* __restrict__ aug,
                                              u16* __restrict__ qt,
                                              u16* __restrict__ obuf,
                                              u16* __restrict__ Sd,
                                              float* __restrict__ Dc,
                                              float* __restrict__ augw) {
    __shared__ __align__(16) float    s_f[64][68];    // gk -> L (cumsum)
    __shared__ __align__(16) _Float16 s_q[64][72];    // q~ rows [t][d]
    __shared__ __align__(16) _Float16 s_k[64][72];    // k~ rows [s][d]
    __shared__ __align__(16) _Float16 s_kT[64][72];   // k~^T rows [d][s]
    __shared__ __align__(16) _Float16 s_a[64][72];    // temp k, then A [t][s]
    __shared__ __align__(16) _Float16 s_vT[128][72];  // V^T rows [dv][s]
    const int c = blockIdx.x, bh = blockIdx.y;
    const int b = bh >> 3, h = bh & 7;
    const int tid = threadIdx.x;
    const size_t rowBase = (size_t)b * LSEQ + c * 64;
    const size_t sdBase = (size_t)bh * NCHUNK + c;

    const int tA = tid >> 2, g4 = tid & 3;
    uint4 qr0, qr1;
    {
        const int d0 = g4 * 16;
        const u16* kp = kg + (rowBase + tA) * DK + h * 64 + d0;
        const uint4 k0 = *(const uint4*)kp;
        const uint4 k1 = *(const uint4*)(kp + 8);
        const u16 kv[16] = {
            (u16)(k0.x & 0xffff), (u16)(k0.x >> 16), (u16)(k0.y & 0xffff), (u16)(k0.y >> 16),
            (u16)(k0.z & 0xffff), (u16)(k0.z >> 16), (u16)(k0.w & 0xffff), (u16)(k0.w >> 16),
            (u16)(k1.x & 0xffff), (u16)(k1.x >> 16), (u16)(k1.y & 0xffff), (u16)(k1.y >> 16),
            (u16)(k1.z & 0xffff), (u16)(k1.z >> 16), (u16)(k1.w & 0xffff), (u16)(k1.w >> 16) };
#pragma unroll
        for (int j = 0; j < 16; j++) {
            const float xk = bf2f(kv[j]);
            const float ls = fminf(xk, 0.f) - __logf(1.f + __expf(-fabsf(xk)));
            s_f[tA][d0 + j] = ls * (1.f / 16.f);
        }
        const u16* qp = q + (rowBase + tA) * DK + h * 64 + d0;
        qr0 = *(const uint4*)qp;
        qr1 = *(const uint4*)(qp + 8);

        const int dv0 = g4 * 32;
        const u16* vp = v + (rowBase + tA) * E + h * 128 + dv0;
#pragma unroll
        for (int j8 = 0; j8 < 32; j8 += 8) {
            const uint4 u = *(const uint4*)(vp + j8);
            s_vT[dv0 + j8 + 0][tA] = (_Float16)bf2f((u16)(u.x & 0xffff));
            s_vT[dv0 + j8 + 1][tA] = (_Float16)bf2f((u16)(u.x >> 16));
            s_vT[dv0 + j8 + 2][tA] = (_Float16)bf2f((u16)(u.y & 0xffff));
            s_vT[dv0 + j8 + 3][tA] = (_Float16)bf2f((u16)(u.y >> 16));
            s_vT[dv0 + j8 + 4][tA] = (_Float16)bf2f((u16)(u.z & 0xffff));
            s_vT[dv0 + j8 + 5][tA] = (_Float16)bf2f((u16)(u.z >> 16));
            s_vT[dv0 + j8 + 6][tA] = (_Float16)bf2f((u16)(u.w & 0xffff));
            s_vT[dv0 + j8 + 7][tA] = (_Float16)bf2f((u16)(u.w >> 16));
        }
    }
    __syncthreads();

    {
        const int d = tid >> 2, qseg = tid & 3;
        float part = 0.f;
#pragma unroll
        for (int j = 0; j < 16; j++) part += s_f[qseg * 16 + j][d];
        float incl = part;
        const float u1 = __shfl_up(incl, 1, 4); if (qseg >= 1) incl += u1;
        const float u2 = __shfl_up(incl, 2, 4); if (qseg >= 2) incl += u2;
        float run = incl - part;   // exclusive prefix
#pragma unroll
        for (int j = 0; j < 16; j++) {
            const int t = qseg * 16 + j;
            const float g = s_f[t][d];
            run += g;
            const float kk = 1.f - __expf(g);
            const float ktil = kk * __expf(-run);
            s_k[t][d] = (_Float16)ktil;
            s_kT[d][t] = (_Float16)ktil;
            s_a[t][d] = (_Float16)kk;
            s_f[t][d] = run;    // L (inclusive)
        }
    }
    __syncthreads();

    {
        const int t = tA, d0 = g4 * 16;
        const u16 qv16[16] = {
            (u16)(qr0.x & 0xffff), (u16)(qr0.x >> 16), (u16)(qr0.y & 0xffff), (u16)(qr0.y >> 16),
            (u16)(qr0.z & 0xffff), (u16)(qr0.z >> 16), (u16)(qr0.w & 0xffff), (u16)(qr0.w >> 16),
            (u16)(qr1.x & 0xffff), (u16)(qr1.x >> 16), (u16)(qr1.y & 0xffff), (u16)(qr1.y >> 16),
            (u16)(qr1.z & 0xffff), (u16)(qr1.z >> 16), (u16)(qr1.w & 0xffff), (u16)(qr1.w >> 16) };
        float qv[16];
        float augp = 0.f;
#pragma unroll
        for (int j = 0; j < 16; j++) {
            const int d = d0 + j;
            const float qraw = bf2f(qv16[j]);
            const float L = s_f[t][d];
            const float kk = (float)s_a[t][d];
            const float qtv = qraw * __expf(L) * 0.125f;   // scale 64^-0.5
            s_q[t][d] = (_Float16)qtv;
            qv[j] = qtv;
            augp = fmaf(qraw * aug[h * 64 + d], kk, augp);
        }
        u16* qto = qt + (rowBase + t) * DK + h * 64 + d0;
#pragma unroll
        for (int j8 = 0; j8 < 16; j8 += 8) {
            uint4 u;
            u.x = (u32)f2bf(qv[j8 + 0]) | ((u32)f2bf(qv[j8 + 1]) << 16);
            u.y = (u32)f2bf(qv[j8 + 2]) | ((u32)f2bf(qv[j8 + 3]) << 16);
            u.z = (u32)f2bf(qv[j8 + 4]) | ((u32)f2bf(qv[j8 + 5]) << 16);
            u.w = (u32)f2bf(qv[j8 + 6]) | ((u32)f2bf(qv[j8 + 7]) << 16);
            *(uint4*)(qto + j8) = u;
        }
        augp += __shfl_xor(augp, 1);
        augp += __shfl_xor(augp, 2);
        if ((tid & 3) == 0) augw[(size_t)bh * LSEQ + c * 64 + t] = augp;
    }
    __syncthreads();

    const int wv = tid >> 6, lane = tid & 63;
    const int rsub = lane & 15, kq8 = (lane >> 4) * 8, r0 = (lane >> 4) * 4;
    {
#pragma unroll
        for (int si = 0; si < 4; si++) {
            if (si <= wv) {
                f32x4 acc = (f32x4){0.f, 0.f, 0.f, 0.f};
#pragma unroll
                for (int kk = 0; kk < 2; kk++) {
                    const f16x8 af = *(const f16x8*)&s_q[wv * 16 + rsub][kk * 32 + kq8];
                    const f16x8 bf = *(const f16x8*)&s_k[si * 16 + rsub][kk * 32 + kq8];
                    acc = __builtin_amdgcn_mfma_f32_16x16x32_f16(af, bf, acc, 0, 0, 0);
                }
                const int scol = si * 16 + rsub;
#pragma unroll
                for (int r = 0; r < 4; r++) {
                    const int trow = wv * 16 + r0 + r;
                    const float val = (scol <= trow) ? acc[r] : 0.f;
                    s_a[trow][scol] = (_Float16)val;
                }
            } else {
#pragma unroll
                for (int r = 0; r < 4; r++)
                    s_a[wv * 16 + r0 + r][si * 16 + rsub] = (_Float16)0.f;
            }
        }
    }
    __syncthreads();

    {
        f32x4 oacc[8];
#pragma unroll
        for (int n = 0; n < 8; n++) oacc[n] = (f32x4){0.f, 0.f, 0.f, 0.f};
        const f16x8 a0 = *(const f16x8*)&s_a[wv * 16 + rsub][kq8];
        const f16x8 a1 = *(const f16x8*)&s_a[wv * 16 + rsub][32 + kq8];
#pragma unroll
        for (int n = 0; n < 8; n++) {
            const f16x8 b0 = *(const f16x8*)&s_vT[n * 16 + rsub][kq8];
            const f16x8 b1 = *(const f16x8*)&s_vT[n * 16 + rsub][32 + kq8];
            oacc[n] = __builtin_amdgcn_mfma_f32_16x16x32_f16(a0, b0, oacc[n], 0, 0, 0);
            oacc[n] = __builtin_amdgcn_mfma_f32_16x16x32_f16(a1, b1, oacc[n], 0, 0, 0);
        }
        u16* ob = obuf + ((size_t)bh * LSEQ + c * 64) * DVH;
#pragma unroll
        for (int n = 0; n < 8; n++) {
            const int dv = n * 16 + rsub;
#pragma unroll
            for (int r = 0; r < 4; r++) {
                const int trow = wv * 16 + r0 + r;
                ob[(size_t)trow * DVH + dv] = f2bf(oacc[n][r]);
            }
        }
    }

    {
        f32x4 sacc[8];
#pragma unroll
        for (int n = 0; n < 8; n++) sacc[n] = (f32x4){0.f, 0.f, 0.f, 0.f};
        const f16x8 a0 = *(const f16x8*)&s_kT[wv * 16 + rsub][kq8];
        const f16x8 a1 = *(const f16x8*)&s_kT[wv * 16 + rsub][32 + kq8];
#pragma unroll
        for (int n = 0; n < 8; n++) {
            const f16x8 b0 = *(const f16x8*)&s_vT[n * 16 + rsub][kq8];
            const f16x8 b1 = *(const f16x8*)&s_vT[n * 16 + rsub][32 + kq8];
            sacc[n] = __builtin_amdgcn_mfma_f32_16x16x32_f16(a0, b0, sacc[n], 0, 0, 0);
            sacc[n] = __builtin_amdgcn_mfma_f32_16x16x32_f16(a1, b1, sacc[n], 0, 0, 0);
        }
        float dend[4];
#pragma unroll
        for (int r = 0; r < 4; r++) dend[r] = __expf(s_f[63][wv * 16 + r0 + r]);
#pragma unroll
        for (int n = 0; n < 8; n++) {
            const int dv = n * 16 + rsub;
#pragma unroll
            for (int r = 0; r < 4; r++) {
                const int d = wv * 16 + r0 + r;
                Sd[(sdBase * DKH + d) * DVH + dv] = f2bf(sacc[n][r] * dend[r]);
            }
        }
        if (rsub == 0) {
#pragma unroll
            for (int r = 0; r < 4; r++) {
                const int d = wv * 16 + r0 + r;
                Dc[sdBase * DKH + d] = dend[r];
            }
        }
    }
}

// ---------------------------------------------- GLA phase 2: chunk-state scan
__global__ __launch_bounds__(256) void k_gla2(const u16* __restrict__ Sd,
                                              u16* __restrict__ Ss,
                                              const float* __restrict__ Dc) {
    const int cid = blockIdx.x * 256 + threadIdx.x;   // 0..262143
    const int bh = cid >> 13;
    const int e = cid & 8191;
    const int d = e >> 7;
    float run = 0.f;
    const size_t base = (size_t)bh * NCHUNK * 8192 + e;
    for (int c = 0; c < NCHUNK; c++) {
        const size_t idx = base + (size_t)c * 8192;
        const float dl = bf2f(Sd[idx]);
        Ss[idx] = f2bf(run);
        run = fmaf(Dc[((size_t)bh * NCHUNK + c) * DKH + d], run, dl);
    }
}

// -------------------- GLA phase 3: MFMA inter-chunk + aug + LN + silu-gate
__global__ __launch_bounds__(256) void k_gla3(const u16* __restrict__ qt,
                                              const u16* __restrict__ v,
                                              const u16* __restrict__ sg,
                                              const u16* __restrict__ obuf,
                                              const u16* __restrict__ Ss,
                                              const float* __restrict__ augw,
                                              u16* __restrict__ a2) {
    __shared__ __align__(16) _Float16 s_ST[128][72];  // S^T rows [dv][d]
    __shared__ __align__(16) _Float16 s_qr[64][72];   // q~ rows [t][d]
    __shared__ __align__(16) float    s_O2[64][132];  // q~ @ S  [t][dv]
    const int c = blockIdx.x, bh = blockIdx.y;
    const int b = bh >> 3, h = bh & 7;
    const int tid = threadIdx.x;
    const size_t rowBase = (size_t)b * LSEQ + c * 64;
    {
        const int d = tid >> 2, dv0 = (tid & 3) * 32;
        const u16* sp = Ss + (((size_t)bh * NCHUNK + c) * DKH + d) * DVH + dv0;
#pragma unroll
        for (int j8 = 0; j8 < 32; j8 += 8) {
            const uint4 u = *(const uint4*)(sp + j8);
            s_ST[dv0 + j8 + 0][d] = (_Float16)bf2f((u16)(u.x & 0xffff));
            s_ST[dv0 + j8 + 1][d] = (_Float16)bf2f((u16)(u.x >> 16));
            s_ST[dv0 + j8 + 2][d] = (_Float16)bf2f((u16)(u.y & 0xffff));
            s_ST[dv0 + j8 + 3][d] = (_Float16)bf2f((u16)(u.y >> 16));
            s_ST[dv0 + j8 + 4][d] = (_Float16)bf2f((u16)(u.z & 0xffff));
            s_ST[dv0 + j8 + 5][d] = (_Float16)bf2f((u16)(u.z >> 16));
            s_ST[dv0 + j8 + 6][d] = (_Float16)bf2f((u16)(u.w & 0xffff));
            s_ST[dv0 + j8 + 7][d] = (_Float16)bf2f((u16)(u.w >> 16));
        }
    }
    {
        const int t = tid >> 2, d0 = (tid & 3) * 16;
        const u16* qp = qt + (rowBase + t) * DK + h * 64 + d0;
        const uint4 q0 = *(const uint4*)qp;
        const uint4 q1 = *(const uint4*)(qp + 8);
        const u16 qv[16] = {
            (u16)(q0.x & 0xffff), (u16)(q0.x >> 16), (u16)(q0.y & 0xffff), (u16)(q0.y >> 16),
            (u16)(q0.z & 0xffff), (u16)(q0.z >> 16), (u16)(q0.w & 0xffff), (u16)(q0.w >> 16),
            (u16)(q1.x & 0xffff), (u16)(q1.x >> 16), (u16)(q1.y & 0xffff), (u16)(q1.y >> 16),
            (u16)(q1.z & 0xffff), (u16)(q1.z >> 16), (u16)(q1.w & 0xffff), (u16)(q1.w >> 16) };
#pragma unroll
        for (int j = 0; j < 16; j++) s_qr[t][d0 + j] = (_Float16)bf2f(qv[j]);
    }
    __syncthreads();
    {
        const int wv = tid >> 6, lane = tid & 63;
        const int rsub = lane & 15, kq8 = (lane >> 4) * 8, r0 = (lane >> 4) * 4;
        const f16x8 a0 = *(const f16x8*)&s_qr[wv * 16 + rsub][kq8];
        const f16x8 a1 = *(const f16x8*)&s_qr[wv * 16 + rsub][32 + kq8];
#pragma unroll
        for (int n = 0; n < 8; n++) {
            f32x4 acc = (f32x4){0.f, 0.f, 0.f, 0.f};
            const f16x8 b0 = *(const f16x8*)&s_ST[n * 16 + rsub][kq8];
            const f16x8 b1 = *(const f16x8*)&s_ST[n * 16 + rsub][32 + kq8];
            acc = __builtin_amdgcn_mfma_f32_16x16x32_f16(a0, b0, acc, 0, 0, 0);
            acc = __builtin_amdgcn_mfma_f32_16x16x32_f16(a1, b1, acc, 0, 0, 0);
            const int dv = n * 16 + rsub;
#pragma unroll
            for (int r = 0; r < 4; r++) s_O2[wv * 16 + r0 + r][dv] = acc[r];
        }
    }
    __syncthreads();
    const int t = tid >> 2, dv0 = (tid & 3) * 32;
    float o[32];
    const u16* op = obuf + ((size_t)bh * LSEQ + c * 64 + t) * DVH + dv0;
#pragma unroll
    for (int j8 = 0; j8 < 32; j8 += 8) {
        const uint4 u = *(const uint4*)(op + j8);
        o[j8 + 0] = bf2f((u16)(u.x & 0xffff)); o[j8 + 1] = bf2f((u16)(u.x >> 16));
        o[j8 + 2] = bf2f((u16)(u.y & 0xffff)); o[j8 + 3] = bf2f((u16)(u.y >> 16));
        o[j8 + 4] = bf2f((u16)(u.z & 0xffff)); o[j8 + 5] = bf2f((u16)(u.z >> 16));
        o[j8 + 6] = bf2f((u16)(u.w & 0xffff)); o[j8 + 7] = bf2f((u16)(u.w >> 16));
    }
#pragma unroll
    for (int j = 0; j < 32; j += 4) {
        const f32x4 sv = *(const f32x4*)&s_O2[t][dv0 + j];
        o[j + 0] += sv[0]; o[j + 1] += sv[1]; o[j + 2] += sv[2]; o[j + 3] += sv[3];
    }
    const float aw = augw[(size_t)bh * LSEQ + c * 64 + t];
    const u16* vp = v + (rowBase + t) * E + h * 128 + dv0;
#pragma unroll
    for (int j8 = 0; j8 < 32; j8 += 8) {
        const uint4 u = *(const uint4*)(vp + j8);
        const float vv[8] = {
            bf2f((u16)(u.x & 0xffff)), bf2f((u16)(u.x >> 16)),
            bf2f((u16)(u.y & 0xffff)), bf2f((u16)(u.y >> 16)),
            bf2f((u16)(u.z & 0xffff)), bf2f((u16)(u.z >> 16)),
            bf2f((u16)(u.w & 0xffff)), bf2f((u16)(u.w >> 16)) };
#pragma unroll
        for (int j = 0; j < 8; j++)
            o[j8 + j] += 1.f / (1.f + __expf(-aw * vv[j]));
    }
    float sum = 0.f;
#pragma unroll
    for (int j = 0; j < 32; j++) sum += o[j];
    sum += __shfl_xor(sum, 1); sum += __shfl_xor(sum, 2);
    const float mu = sum * (1.f / 128.f);
    float sq = 0.f;
#pragma unroll
    for (int j = 0; j < 32; j++) { const float dlt = o[j] - mu; sq = fmaf(dlt, dlt, sq); }
    sq += __shfl_xor(sq, 1); sq += __shfl_xor(sq, 2);
    const float rs = rsqrtf(sq * (1.f / 128.f) + LN_EPS);
    const u16* sp2 = sg + (rowBase + t) * E + h * 128 + dv0;
    u16* ap = a2 + (rowBase + t) * E + h * 128 + dv0;
#pragma unroll
    for (int j8 = 0; j8 < 32; j8 += 8) {
        const uint4 us = *(const uint4*)(sp2 + j8);
        const float sv[8] = {
            bf2f((u16)(us.x & 0xffff)), bf2f((u16)(us.x >> 16)),
            bf2f((u16)(us.y & 0xffff)), bf2f((u16)(us.y >> 16)),
            bf2f((u16)(us.z & 0xffff)), bf2f((u16)(us.z >> 16)),
            bf2f((u16)(us.w & 0xffff)), bf2f((u16)(us.w >> 16)) };
        uint4 u;
        u.x = (u32)f2bf(sv[0] * ((o[j8 + 0] - mu) * rs)) | ((u32)f2bf(sv[1] * ((o[j8 + 1] - mu) * rs)) << 16);
        u.y = (u32)f2bf(sv[2] * ((o[j8 + 2] - mu) * rs)) | ((u32)f2bf(sv[3] * ((o[j8 + 3] - mu) * rs)) << 16);
        u.z = (u32)f2bf(sv[4] * ((o[j8 + 4] - mu) * rs)) | ((u32)f2bf(sv[5] * ((o[j8 + 5] - mu) * rs)) << 16);
        u.w = (u32)f2bf(sv[6] * ((o[j8 + 6] - mu) * rs)) | ((u32)f2bf(sv[7] * ((o[j8 + 7] - mu) * rs)) << 16);
        *(uint4*)(ap + j8) = u;
    }
}

// ----------------------------------------------------------------- launcher
extern "C" void kernel_launch(void* const* d_in, const int* in_sizes, int n_in,
                              void* d_out, int out_size, void* d_ws, size_t ws_size,
                              hipStream_t stream) {
    const float* x      = (const float*)d_in[0];
    const float* conv_w = (const float*)d_in[1];
    const float* wq     = (const float*)d_in[2];
    const float* wkg    = (const float*)d_in[3];
    const float* wv     = (const float*)d_in[4];
    const float* wg     = (const float*)d_in[5];
    const float* bg     = (const float*)d_in[6];
    const float* wout   = (const float*)d_in[7];
    const float* aug    = (const float*)d_in[8];

    char* ws = (char*)d_ws;
    size_t off = 0;
    auto alloc = [&](size_t bytes) -> char* {
        char* p = ws + off;
        off += (bytes + 255) & ~(size_t)255;
        return p;
    };
    u16* xc    = (u16*)alloc((size_t)MROWS * E * 2);
    u16* wcat  = (u16*)alloc((size_t)3072 * E * 2);
    u16* woutT = (u16*)alloc((size_t)E * E * 2);
    u16* qb    = (u16*)alloc((size_t)MROWS * DK * 2);
    u16* kgb   = (u16*)alloc((size_t)MROWS * DK * 2);
    u16* vb    = (u16*)alloc((size_t)MROWS * E * 2);
    u16* sgb   = (u16*)alloc((size_t)MROWS * E * 2);
    u16* qtb   = (u16*)alloc((size_t)MROWS * DK * 2);
    u16* obuf  = (u16*)alloc((size_t)32 * LSEQ * DVH * 2);
    u16* Ssb   = (u16*)alloc((size_t)32 * NCHUNK * DKH * DVH * 2);  // 16.8 MB
    float* Dc  = (float*)alloc((size_t)32 * NCHUNK * DKH * 4);
    float* augw= (float*)alloc((size_t)32 * LSEQ * 4);
    u16* a2    = qb;                 // reuse q+kg region (dead after gla1)
    u16* Sd    = (u16*)d_out;        // bf16 deltas; overwritten by final GEMM

    k_conv<<<dim3(LSEQ / 64, E / 256, 4), 256, 0, stream>>>(x, conv_w, xc);
    k_transpose_all<<<dim3(32, 32, 5), 256, 0, stream>>>(wq, wkg, wv, wg, wout, wcat, woutT);
    k_gemm0<<<512, 512, 0, stream>>>(xc, wcat, qb, kgb, vb, sgb, bg);
    k_gla1<<<dim3(NCHUNK, 32), 256, 0, stream>>>(qb, kgb, vb, aug, qtb, obuf, Sd, Dc, augw);
    k_gla2<<<1024, 256, 0, stream>>>(Sd, Ssb, Dc);
    k_gla3<<<dim3(NCHUNK, 32), 256, 0, stream>>>(qtb, vb, sgb, obuf, Ssb, augw, a2);
    k_gemm1<<<dim3(32, 8), 512, 0, stream>>>(a2, woutT, (float*)d_out);
}

// Round 18
// 153.596 us; speedup vs baseline: 1.0269x; 1.0269x over previous
//
#include <hip/hip_runtime.h>
#include <stdint.h>

typedef unsigned short u16;
typedef unsigned int u32;
typedef __attribute__((ext_vector_type(4))) float f32x4;
typedef __attribute__((ext_vector_type(8))) short short8;
typedef __attribute__((ext_vector_type(8))) _Float16 f16x8;

#define H 8
#define LSEQ 2048
#define E 1024
#define DK 512
#define DVH 128
#define DKH 64
#define NCHUNK 32
#define MROWS 8192
#define LN_EPS 1e-5f

#define AS1 __attribute__((address_space(1)))
#define AS3 __attribute__((address_space(3)))

static __device__ __forceinline__ float bf2f(u16 u) {
    union { float f; u32 i; } v; v.i = ((u32)u) << 16; return v.f;
}
static __device__ __forceinline__ u16 f2bf(float f) {
    union { float f; u32 i; } v; v.f = f;
    u32 r = v.i + 0x7FFFu + ((v.i >> 16) & 1u);
    return (u16)(r >> 16);
}

// --------------------------- fused conv+silu / weight transpose+cast kernel
// blocks 0..511: causal dwconv+silu (x -> xc bf16), sliding window.
// blocks 512..5631: 32x32 transpose+cast of the 5 weights.
__global__ __launch_bounds__(256) void k_pre(const float* __restrict__ x,
                                             const float* __restrict__ cw,
                                             u16* __restrict__ xc,
                                             const float* __restrict__ wq,
                                             const float* __restrict__ wkg,
                                             const float* __restrict__ wv,
                                             const float* __restrict__ wg,
                                             const float* __restrict__ wout,
                                             u16* __restrict__ wcat,
                                             u16* __restrict__ woutT) {
    __shared__ float tile[32][33];
    const int bid = blockIdx.x;
    if (bid < 512) {
        // conv: cx 0..31 (l0), cy 0..3 (col block), b 0..3
        const int cx = bid & 31;
        const int cy = (bid >> 5) & 3;
        const int b  = bid >> 7;
        const int l0 = cx * 64;
        const int c  = cy * 256 + threadIdx.x;
        const f32x4 w = *(const f32x4*)(cw + c * 4);
        const float* base = x + (size_t)b * LSEQ * E + c;
        u16* ob = xc + (size_t)b * LSEQ * E + c;
        float x3 = (l0 >= 3) ? base[(size_t)(l0 - 3) * E] : 0.f;
        float x2 = (l0 >= 2) ? base[(size_t)(l0 - 2) * E] : 0.f;
        float x1 = (l0 >= 1) ? base[(size_t)(l0 - 1) * E] : 0.f;
#pragma unroll 8
        for (int r = 0; r < 64; r++) {
            const float x0 = base[(size_t)(l0 + r) * E];
            float a = x3 * w[0];
            a = fmaf(x2, w[1], a);
            a = fmaf(x1, w[2], a);
            a = fmaf(x0, w[3], a);
            const float s = a / (1.f + __expf(-a));
            ob[(size_t)(l0 + r) * E] = f2bf(s);
            x3 = x2; x2 = x1; x1 = x0;
        }
    } else {
        const int t = bid - 512;            // 0..5119
        const int nb = t & 31;              // n0/32
        const int kb = (t >> 5) & 31;       // k0/32
        const int z  = t >> 10;             // 0..4
        const float* src; u16* dst; int Ncols;
        if (z == 0)      { src = wq;   dst = wcat;                        Ncols = 512; }
        else if (z == 1) { src = wkg;  dst = wcat + (size_t)512 * 1024;   Ncols = 512; }
        else if (z == 2) { src = wv;   dst = wcat + (size_t)1024 * 1024;  Ncols = 1024; }
        else if (z == 3) { src = wg;   dst = wcat + (size_t)2048 * 1024;  Ncols = 1024; }
        else             { src = wout; dst = woutT;                       Ncols = 1024; }
        const int n0 = nb * 32, k0 = kb * 32;
        if (n0 >= Ncols) return;
        const int K = 1024;
        const int tx = threadIdx.x & 31, ty = threadIdx.x >> 5;   // ty 0..7
#pragma unroll
        for (int p = 0; p < 4; p++) {
            const int r = p * 8 + ty;
            tile[r][tx] = src[(size_t)(k0 + r) * Ncols + n0 + tx];
        }
        __syncthreads();
#pragma unroll
        for (int p = 0; p < 4; p++) {
            const int rn = p * 8 + ty;
            dst[(size_t)(n0 + rn) * K + k0 + tx] = f2bf(tile[tx][rn]);
        }
    }
}

// -------------------------------------------------------- GEMM0 (projection)
// 4-wave blocks: 128x192 tile, BK=32, 3-slot ring (20 KB/slot, 60 KB) ->
// 2 blocks/CU co-resident. Per-wave 64x96. Grid 1024 = 2 resident rounds.
// vmcnt(5)/(0), stage h+2 into retired slot. (Round-14/16 proven config.)
__global__ __launch_bounds__(256, 1) void k_gemm0(const u16* __restrict__ A,
                                                  const u16* __restrict__ Bt,
                                                  u16* __restrict__ oQ, u16* __restrict__ oKG,
                                                  u16* __restrict__ oV, u16* __restrict__ oSG,
                                                  const float* __restrict__ bg) {
    const int K = 1024;
    __shared__ __align__(16) u16 smem[3][10240];
    const int tid = threadIdx.x;
    const int lane = tid & 63, wv = tid >> 6;      // 4 waves
    const int wm = wv >> 1, wn = wv & 1;           // 2M x 2N, 64x96 per wave

    const int id = blockIdx.x;                     // 0..1023
    const int local = id >> 3;                     // 0..127
    const int bx = ((id & 7) << 3) | (local & 7);  // 0..63
    const int by = local >> 3;                     // 0..15

    const size_t rowBase = (size_t)bx * 128;
    const size_t colBase = (size_t)by * 192;

    auto stage = [&](int hh, int sl) {
        u16* slotA = &smem[sl][0];
        u16* slotB = &smem[sl][4096];
        const u16* gA = A + rowBase * K + hh * 32;
        const u16* gB = Bt + colBase * K + hh * 32;
#pragma unroll
        for (int i = 0; i < 2; i++) {               // A: 512 units (128 rows)
            const int u = i * 256 + wv * 64 + lane;
            const int row = u >> 2;
            const int sg = (u & 3) ^ ((row >> 1) & 3);
            __builtin_amdgcn_global_load_lds(
                (const AS1 void*)(gA + (size_t)row * K + sg * 8),
                (AS3 void*)(slotA + (i * 256 + wv * 64) * 8), 16, 0, 0);
        }
#pragma unroll
        for (int i = 0; i < 3; i++) {               // B: 768 units (192 rows)
            const int u = i * 256 + wv * 64 + lane;
            const int row = u >> 2;
            const int sg = (u & 3) ^ ((row >> 1) & 3);
            __builtin_amdgcn_global_load_lds(
                (const AS1 void*)(gB + (size_t)row * K + sg * 8),
                (AS3 void*)(slotB + (i * 256 + wv * 64) * 8), 16, 0, 0);
        }
    };

    f32x4 acc[4][6];
#pragma unroll
    for (int m = 0; m < 4; m++)
#pragma unroll
        for (int n = 0; n < 6; n++) acc[m][n] = (f32x4){0.f, 0.f, 0.f, 0.f};

    const int rsub = lane & 15;
    const int cgl = lane >> 4;   // 0..3

    stage(0, 0); stage(1, 1);

    const int NT2 = K >> 5;   // 32 halves
    for (int h = 0; h < NT2; h++) {
        if (h + 1 < NT2) asm volatile("s_waitcnt vmcnt(5)" ::: "memory");
        else             asm volatile("s_waitcnt vmcnt(0)" ::: "memory");
        asm volatile("s_barrier" ::: "memory");
        const int sl = h % 3;
        const u16* As = &smem[sl][0];
        const u16* Bs = &smem[sl][4096];
        short8 af[4], bfr[6];
#pragma unroll
        for (int mi = 0; mi < 4; mi++) {
            const int row = wm * 64 + mi * 16 + rsub;
            const int g = cgl ^ ((row >> 1) & 3);
            af[mi] = *(const short8*)(As + row * 32 + g * 8);
        }
#pragma unroll
        for (int ni = 0; ni < 6; ni++) {
            const int row = wn * 96 + ni * 16 + rsub;
            const int g = cgl ^ ((row >> 1) & 3);
            bfr[ni] = *(const short8*)(Bs + row * 32 + g * 8);
        }
        if (h + 2 < NT2) stage(h + 2, (h + 2) % 3);
        __builtin_amdgcn_s_setprio(1);
#pragma unroll
        for (int mi = 0; mi < 4; mi++)
#pragma unroll
            for (int ni = 0; ni < 6; ni++)
                acc[mi][ni] = __builtin_amdgcn_mfma_f32_16x16x32_bf16(af[mi], bfr[ni], acc[mi][ni], 0, 0, 0);
        __builtin_amdgcn_s_setprio(0);
    }

    // ---- epilogue: single-pass 128x192 repack (48 KB over the 3 slots)
    const int r0 = (lane >> 4) * 4;
    u16* lds = &smem[0][0];
    __syncthreads();
#pragma unroll
    for (int ni = 0; ni < 6; ni++) {
        const int colg = (int)colBase + wn * 96 + ni * 16 + rsub;
        const bool isSG = (colg >= 2048);
        const float bgv = isSG ? bg[colg - 2048] : 0.f;
        const int lcol = wn * 96 + ni * 16 + rsub;
#pragma unroll
        for (int mi = 0; mi < 4; mi++) {
#pragma unroll
            for (int r = 0; r < 4; r++) {
                const int lrow = wm * 64 + mi * 16 + r0 + r;
                float val = acc[mi][ni][r];
                if (isSG) { const float y = val + bgv; val = y / (1.f + __expf(-y)); }
                lds[lrow * 192 + lcol] = f2bf(val);
            }
        }
    }
    __syncthreads();
#pragma unroll
    for (int sp = 0; sp < 3; sp++) {
        const int gc = (int)colBase + sp * 64;
        u16* seg; int stride; int c0;
        if (gc < 512)       { seg = oQ;  stride = 512;  c0 = gc; }
        else if (gc < 1024) { seg = oKG; stride = 512;  c0 = gc - 512; }
        else if (gc < 2048) { seg = oV;  stride = 1024; c0 = gc - 1024; }
        else                { seg = oSG; stride = 1024; c0 = gc - 2048; }
#pragma unroll
        for (int i = 0; i < 4; i++) {
            const int unit = i * 256 + tid;
            const int row = unit >> 3, uu = unit & 7;
            const uint4 vv = *(const uint4*)(lds + row * 192 + sp * 64 + uu * 8);
            *(uint4*)(seg + (rowBase + row) * (size_t)stride + c0 + uu * 8) = vv;
        }
    }
}

// ------------------------------------------------------------ GEMM1 (output)
__global__ __launch_bounds__(512, 1) void k_gemm1(const u16* __restrict__ A,
                                                  const u16* __restrict__ Bt,
                                                  float* __restrict__ oF) {
    const int K = 1024, N = 1024;
    __shared__ __align__(16) u16 smem[4][12288];   // 96 KB
    const int tid = threadIdx.x;
    const int lane = tid & 63, wv = tid >> 6;
    const int wm = wv >> 1, wn = wv & 1;

    const int id = blockIdx.y * gridDim.x + blockIdx.x;
    const int bx = ((id & 7) << 2) | ((id >> 3) & 3);
    const int by = id >> 5;

    const size_t rowBase = (size_t)bx * 256;
    const size_t colBase = (size_t)by * 128;

    auto stageA = [&](int hh) {
        u16* slotA = &smem[hh & 3][0];
        const u16* g = A + rowBase * K + hh * 32;
#pragma unroll
        for (int i = 0; i < 2; i++) {
            const int r = i * 128 + wv * 16 + (lane >> 2);
            const int sg = (lane & 3) ^ ((r >> 1) & 3);
            __builtin_amdgcn_global_load_lds(
                (const AS1 void*)(g + (size_t)r * K + sg * 8),
                (AS3 void*)(slotA + i * 4096 + wv * 512), 16, 0, 0);
        }
    };
    auto stageB = [&](int hh) {
        u16* slotB = &smem[hh & 3][8192];
        const u16* g = Bt + colBase * K + hh * 32;
        const int r = wv * 16 + (lane >> 2);
        const int sg = (lane & 3) ^ ((r >> 1) & 3);
        __builtin_amdgcn_global_load_lds(
            (const AS1 void*)(g + (size_t)r * K + sg * 8),
            (AS3 void*)(slotB + wv * 512), 16, 0, 0);
    };

    f32x4 acc[4][4];
#pragma unroll
    for (int m = 0; m < 4; m++)
#pragma unroll
        for (int n = 0; n < 4; n++) acc[m][n] = (f32x4){0.f, 0.f, 0.f, 0.f};

    const int rsub = lane & 15;
    const int cgl = lane >> 4;

    stageA(0); stageB(0);
    stageA(1); stageB(1);
    stageA(2); stageB(2);

    const int NT2 = K >> 5;
    for (int h = 0; h < NT2; h++) {
        const int rem = NT2 - 1 - h;
        if (rem >= 2)      asm volatile("s_waitcnt vmcnt(6)" ::: "memory");
        else if (rem == 1) asm volatile("s_waitcnt vmcnt(3)" ::: "memory");
        else               asm volatile("s_waitcnt vmcnt(0)" ::: "memory");
        asm volatile("s_barrier" ::: "memory");
        const u16* As = &smem[h & 3][0];
        const u16* Bs = As + 8192;
        short8 af[4], bfr[4];
#pragma unroll
        for (int mi = 0; mi < 4; mi++) {
            const int row = wm * 64 + mi * 16 + rsub;
            const int g = cgl ^ ((row >> 1) & 3);
            af[mi] = *(const short8*)(As + row * 32 + g * 8);
        }
#pragma unroll
        for (int ni = 0; ni < 4; ni++) {
            const int row = wn * 64 + ni * 16 + rsub;
            const int g = cgl ^ ((row >> 1) & 3);
            bfr[ni] = *(const short8*)(Bs + row * 32 + g * 8);
        }
        if (h + 3 < NT2) { stageA(h + 3); stageB(h + 3); }
        __builtin_amdgcn_s_setprio(1);
#pragma unroll
        for (int mi = 0; mi < 4; mi++)
#pragma unroll
            for (int ni = 0; ni < 4; ni++)
                acc[mi][ni] = __builtin_amdgcn_mfma_f32_16x16x32_bf16(af[mi], bfr[ni], acc[mi][ni], 0, 0, 0);
        __builtin_amdgcn_s_setprio(0);
    }

    // ---- epilogue: two 128-row passes via padded f32 LDS [128][132]
    const int r0 = (lane >> 4) * 4;
    float* lf = (float*)&smem[0][0];   // 128*132*4 = 67584 B <= 96 KB
#pragma unroll
    for (int p = 0; p < 2; p++) {
        __syncthreads();
        if ((wm >> 1) == p) {
            const int wml = wm & 1;
#pragma unroll
            for (int mi = 0; mi < 4; mi++)
#pragma unroll
                for (int ni = 0; ni < 4; ni++) {
                    const int lcol = wn * 64 + ni * 16 + rsub;
#pragma unroll
                    for (int r = 0; r < 4; r++) {
                        const int lrow = wml * 64 + mi * 16 + r0 + r;
                        lf[lrow * 132 + lcol] = acc[mi][ni][r];
                    }
                }
        }
        __syncthreads();
#pragma unroll
        for (int i = 0; i < 8; i++) {
            const int unit = i * 512 + tid;
            const int row = unit >> 5, u = unit & 31;
            const f32x4 vv = *(const f32x4*)(lf + row * 132 + u * 4);
            *(f32x4*)(oF + (rowBase + p * 128 + row) * (size_t)N + colBase + u * 4) = vv;
        }
    }
}

// ------------------------------------------------------- GLA phase 1 (intra)
__global__ __launch_bounds__(256) void k_gla1(const u16* __restrict__ q,
                                              const u16* __restrict__ kg,
                                              const u16* __restrict__ v,
                                              const float* __restrict__ aug,
                                              u16* __restrict__ qt,
                                              u16* __restrict__ obuf,
                                              u16* __restrict__ Sd,
                                              float* __restrict__ Dc,
                                              float* __restrict__ augw) {
    __shared__ __align__(16) float    s_f[64][68];    // gk -> L (cumsum)
    __shared__ __align__(16) _Float16 s_q[64][72];    // q~ rows [t][d]
    __shared__ __align__(16) _Float16 s_k[64][72];    // k~ rows [s][d]
    __shared__ __align__(16) _Float16 s_kT[64][72];   // k~^T rows [d][s]
    __shared__ __align__(16) _Float16 s_a[64][72];    // temp k, then A [t][s]
    __shared__ __align__(16) _Float16 s_vT[128][72];  // V^T rows [dv][s]
    const int c = blockIdx.x, bh = blockIdx.y;
    const int b = bh >> 3, h = bh & 7;
    const int tid = threadIdx.x;
    const size_t rowBase = (size_t)b * LSEQ + c * 64;
    const size_t sdBase = (size_t)bh * NCHUNK + c;

    const int tA = tid >> 2, g4 = tid & 3;
    uint4 qr0, qr1;
    {
        const int d0 = g4 * 16;
        const u16* kp = kg + (rowBase + tA) * DK + h * 64 + d0;
        const uint4 k0 = *(const uint4*)kp;
        const uint4 k1 = *(const uint4*)(kp + 8);
        const u16 kv[16] = {
            (u16)(k0.x & 0xffff), (u16)(k0.x >> 16), (u16)(k0.y & 0xffff), (u16)(k0.y >> 16),
            (u16)(k0.z & 0xffff), (u16)(k0.z >> 16), (u16)(k0.w & 0xffff), (u16)(k0.w >> 16),
            (u16)(k1.x & 0xffff), (u16)(k1.x >> 16), (u16)(k1.y & 0xffff), (u16)(k1.y >> 16),
            (u16)(k1.z & 0xffff), (u16)(k1.z >> 16), (u16)(k1.w & 0xffff), (u16)(k1.w >> 16) };
#pragma unroll
        for (int j = 0; j < 16; j++) {
            const float xk = bf2f(kv[j]);
            const float ls = fminf(xk, 0.f) - __logf(1.f + __expf(-fabsf(xk)));
            s_f[tA][d0 + j] = ls * (1.f / 16.f);
        }
        const u16* qp = q + (rowBase + tA) * DK + h * 64 + d0;
        qr0 = *(const uint4*)qp;
        qr1 = *(const uint4*)(qp + 8);

        const int dv0 = g4 * 32;
        const u16* vp = v + (rowBase + tA) * E + h * 128 + dv0;
#pragma unroll
        for (int j8 = 0; j8 < 32; j8 += 8) {
            const uint4 u = *(const uint4*)(vp + j8);
            s_vT[dv0 + j8 + 0][tA] = (_Float16)bf2f((u16)(u.x & 0xffff));
            s_vT[dv0 + j8 + 1][tA] = (_Float16)bf2f((u16)(u.x >> 16));
            s_vT[dv0 + j8 + 2][tA] = (_Float16)bf2f((u16)(u.y & 0xffff));
            s_vT[dv0 + j8 + 3][tA] = (_Float16)bf2f((u16)(u.y >> 16));
            s_vT[dv0 + j8 + 4][tA] = (_Float16)bf2f((u16)(u.z & 0xffff));
            s_vT[dv0 + j8 + 5][tA] = (_Float16)bf2f((u16)(u.z >> 16));
            s_vT[dv0 + j8 + 6][tA] = (_Float16)bf2f((u16)(u.w & 0xffff));
            s_vT[dv0 + j8 + 7][tA] = (_Float16)bf2f((u16)(u.w >> 16));
        }
    }
    __syncthreads();

    {
        const int d = tid >> 2, qseg = tid & 3;
        float part = 0.f;
#pragma unroll
        for (int j = 0; j < 16; j++) part += s_f[qseg * 16 + j][d];
        float incl = part;
        const float u1 = __shfl_up(incl, 1, 4); if (qseg >= 1) incl += u1;
        const float u2 = __shfl_up(incl, 2, 4); if (qseg >= 2) incl += u2;
        float run = incl - part;   // exclusive prefix
#pragma unroll
        for (int j = 0; j < 16; j++) {
            const int t = qseg * 16 + j;
            const float g = s_f[t][d];
            run += g;
            const float kk = 1.f - __expf(g);
            const float ktil = kk * __expf(-run);
            s_k[t][d] = (_Float16)ktil;
            s_kT[d][t] = (_Float16)ktil;
            s_a[t][d] = (_Float16)kk;
            s_f[t][d] = run;    // L (inclusive)
        }
    }
    __syncthreads();

    {
        const int t = tA, d0 = g4 * 16;
        const u16 qv16[16] = {
            (u16)(qr0.x & 0xffff), (u16)(qr0.x >> 16), (u16)(qr0.y & 0xffff), (u16)(qr0.y >> 16),
            (u16)(qr0.z & 0xffff), (u16)(qr0.z >> 16), (u16)(qr0.w & 0xffff), (u16)(qr0.w >> 16),
            (u16)(qr1.x & 0xffff), (u16)(qr1.x >> 16), (u16)(qr1.y & 0xffff), (u16)(qr1.y >> 16),
            (u16)(qr1.z & 0xffff), (u16)(qr1.z >> 16), (u16)(qr1.w & 0xffff), (u16)(qr1.w >> 16) };
        float qv[16];
        float augp = 0.f;
#pragma unroll
        for (int j = 0; j < 16; j++) {
            const int d = d0 + j;
            const float qraw = bf2f(qv16[j]);
            const float L = s_f[t][d];
            const float kk = (float)s_a[t][d];
            const float qtv = qraw * __expf(L) * 0.125f;   // scale 64^-0.5
            s_q[t][d] = (_Float16)qtv;
            qv[j] = qtv;
            augp = fmaf(qraw * aug[h * 64 + d], kk, augp);
        }
        u16* qto = qt + (rowBase + t) * DK + h * 64 + d0;
#pragma unroll
        for (int j8 = 0; j8 < 16; j8 += 8) {
            uint4 u;
            u.x = (u32)f2bf(qv[j8 + 0]) | ((u32)f2bf(qv[j8 + 1]) << 16);
            u.y = (u32)f2bf(qv[j8 + 2]) | ((u32)f2bf(qv[j8 + 3]) << 16);
            u.z = (u32)f2bf(qv[j8 + 4]) | ((u32)f2bf(qv[j8 + 5]) << 16);
            u.w = (u32)f2bf(qv[j8 + 6]) | ((u32)f2bf(qv[j8 + 7]) << 16);
            *(uint4*)(qto + j8) = u;
        }
        augp += __shfl_xor(augp, 1);
        augp += __shfl_xor(augp, 2);
        if ((tid & 3) == 0) augw[(size_t)bh * LSEQ + c * 64 + t] = augp;
    }
    __syncthreads();

    const int wv = tid >> 6, lane = tid & 63;
    const int rsub = lane & 15, kq8 = (lane >> 4) * 8, r0 = (lane >> 4) * 4;
    {
#pragma unroll
        for (int si = 0; si < 4; si++) {
            if (si <= wv) {
                f32x4 acc = (f32x4){0.f, 0.f, 0.f, 0.f};
#pragma unroll
                for (int kk = 0; kk < 2; kk++) {
                    const f16x8 af = *(const f16x8*)&s_q[wv * 16 + rsub][kk * 32 + kq8];
                    const f16x8 bf = *(const f16x8*)&s_k[si * 16 + rsub][kk * 32 + kq8];
                    acc = __builtin_amdgcn_mfma_f32_16x16x32_f16(af, bf, acc, 0, 0, 0);
                }
                const int scol = si * 16 + rsub;
#pragma unroll
                for (int r = 0; r < 4; r++) {
                    const int trow = wv * 16 + r0 + r;
                    const float val = (scol <= trow) ? acc[r] : 0.f;
                    s_a[trow][scol] = (_Float16)val;
                }
            } else {
#pragma unroll
                for (int r = 0; r < 4; r++)
                    s_a[wv * 16 + r0 + r][si * 16 + rsub] = (_Float16)0.f;
            }
        }
    }
    __syncthreads();

    {
        f32x4 oacc[8];
#pragma unroll
        for (int n = 0; n < 8; n++) oacc[n] = (f32x4){0.f, 0.f, 0.f, 0.f};
        const f16x8 a0 = *(const f16x8*)&s_a[wv * 16 + rsub][kq8];
        const f16x8 a1 = *(const f16x8*)&s_a[wv * 16 + rsub][32 + kq8];
#pragma unroll
        for (int n = 0; n < 8; n++) {
            const f16x8 b0 = *(const f16x8*)&s_vT[n * 16 + rsub][kq8];
            const f16x8 b1 = *(const f16x8*)&s_vT[n * 16 + rsub][32 + kq8];
            oacc[n] = __builtin_amdgcn_mfma_f32_16x16x32_f16(a0, b0, oacc[n], 0, 0, 0);
            oacc[n] = __builtin_amdgcn_mfma_f32_16x16x32_f16(a1, b1, oacc[n], 0, 0, 0);
        }
        u16* ob = obuf + ((size_t)bh * LSEQ + c * 64) * DVH;
#pragma unroll
        for (int n = 0; n < 8; n++) {
            const int dv = n * 16 + rsub;
#pragma unroll
            for (int r = 0; r < 4; r++) {
                const int trow = wv * 16 + r0 + r;
                ob[(size_t)trow * DVH + dv] = f2bf(oacc[n][r]);
            }
        }
    }

    {
        f32x4 sacc[8];
#pragma unroll
        for (int n = 0; n < 8; n++) sacc[n] = (f32x4){0.f, 0.f, 0.f, 0.f};
        const f16x8 a0 = *(const f16x8*)&s_kT[wv * 16 + rsub][kq8];
        const f16x8 a1 = *(const f16x8*)&s_kT[wv * 16 + rsub][32 + kq8];
#pragma unroll
        for (int n = 0; n < 8; n++) {
            const f16x8 b0 = *(const f16x8*)&s_vT[n * 16 + rsub][kq8];
            const f16x8 b1 = *(const f16x8*)&s_vT[n * 16 + rsub][32 + kq8];
            sacc[n] = __builtin_amdgcn_mfma_f32_16x16x32_f16(a0, b0, sacc[n], 0, 0, 0);
            sacc[n] = __builtin_amdgcn_mfma_f32_16x16x32_f16(a1, b1, sacc[n], 0, 0, 0);
        }
        float dend[4];
#pragma unroll
        for (int r = 0; r < 4; r++) dend[r] = __expf(s_f[63][wv * 16 + r0 + r]);
#pragma unroll
        for (int n = 0; n < 8; n++) {
            const int dv = n * 16 + rsub;
#pragma unroll
            for (int r = 0; r < 4; r++) {
                const int d = wv * 16 + r0 + r;
                Sd[(sdBase * DKH + d) * DVH + dv] = f2bf(sacc[n][r] * dend[r]);
            }
        }
        if (rsub == 0) {
#pragma unroll
            for (int r = 0; r < 4; r++) {
                const int d = wv * 16 + r0 + r;
                Dc[sdBase * DKH + d] = dend[r];
            }
        }
    }
}

// ---------------------------------------------- GLA phase 2: chunk-state scan
__global__ __launch_bounds__(256) void k_gla2(const u16* __restrict__ Sd,
                                              u16* __restrict__ Ss,
                                              const float* __restrict__ Dc) {
    const int cid = blockIdx.x * 256 + threadIdx.x;   // 0..262143
    const int bh = cid >> 13;
    const int e = cid & 8191;
    const int d = e >> 7;
    float run = 0.f;
    const size_t base = (size_t)bh * NCHUNK * 8192 + e;
    for (int c = 0; c < NCHUNK; c++) {
        const size_t idx = base + (size_t)c * 8192;
        const float dl = bf2f(Sd[idx]);
        Ss[idx] = f2bf(run);
        run = fmaf(Dc[((size_t)bh * NCHUNK + c) * DKH + d], run, dl);
    }
}

// -------------------- GLA phase 3: MFMA inter-chunk + aug + LN + silu-gate
__global__ __launch_bounds__(256) void k_gla3(const u16* __restrict__ qt,
                                              const u16* __restrict__ v,
                                              const u16* __restrict__ sg,
                                              const u16* __restrict__ obuf,
                                              const u16* __restrict__ Ss,
                                              const float* __restrict__ augw,
                                              u16* __restrict__ a2) {
    __shared__ __align__(16) _Float16 s_ST[128][72];  // S^T rows [dv][d]
    __shared__ __align__(16) _Float16 s_qr[64][72];   // q~ rows [t][d]
    __shared__ __align__(16) float    s_O2[64][132];  // q~ @ S  [t][dv]
    const int c = blockIdx.x, bh = blockIdx.y;
    const int b = bh >> 3, h = bh & 7;
    const int tid = threadIdx.x;
    const size_t rowBase = (size_t)b * LSEQ + c * 64;
    {
        const int d = tid >> 2, dv0 = (tid & 3) * 32;
        const u16* sp = Ss + (((size_t)bh * NCHUNK + c) * DKH + d) * DVH + dv0;
#pragma unroll
        for (int j8 = 0; j8 < 32; j8 += 8) {
            const uint4 u = *(const uint4*)(sp + j8);
            s_ST[dv0 + j8 + 0][d] = (_Float16)bf2f((u16)(u.x & 0xffff));
            s_ST[dv0 + j8 + 1][d] = (_Float16)bf2f((u16)(u.x >> 16));
            s_ST[dv0 + j8 + 2][d] = (_Float16)bf2f((u16)(u.y & 0xffff));
            s_ST[dv0 + j8 + 3][d] = (_Float16)bf2f((u16)(u.y >> 16));
            s_ST[dv0 + j8 + 4][d] = (_Float16)bf2f((u16)(u.z & 0xffff));
            s_ST[dv0 + j8 + 5][d] = (_Float16)bf2f((u16)(u.z >> 16));
            s_ST[dv0 + j8 + 6][d] = (_Float16)bf2f((u16)(u.w & 0xffff));
            s_ST[dv0 + j8 + 7][d] = (_Float16)bf2f((u16)(u.w >> 16));
        }
    }
    {
        const int t = tid >> 2, d0 = (tid & 3) * 16;
        const u16* qp = qt + (rowBase + t) * DK + h * 64 + d0;
        const uint4 q0 = *(const uint4*)qp;
        const uint4 q1 = *(const uint4*)(qp + 8);
        const u16 qv[16] = {
            (u16)(q0.x & 0xffff), (u16)(q0.x >> 16), (u16)(q0.y & 0xffff), (u16)(q0.y >> 16),
            (u16)(q0.z & 0xffff), (u16)(q0.z >> 16), (u16)(q0.w & 0xffff), (u16)(q0.w >> 16),
            (u16)(q1.x & 0xffff), (u16)(q1.x >> 16), (u16)(q1.y & 0xffff), (u16)(q1.y >> 16),
            (u16)(q1.z & 0xffff), (u16)(q1.z >> 16), (u16)(q1.w & 0xffff), (u16)(q1.w >> 16) };
#pragma unroll
        for (int j = 0; j < 16; j++) s_qr[t][d0 + j] = (_Float16)bf2f(qv[j]);
    }
    __syncthreads();
    {
        const int wv = tid >> 6, lane = tid & 63;
        const int rsub = lane & 15, kq8 = (lane >> 4) * 8, r0 = (lane >> 4) * 4;
        const f16x8 a0 = *(const f16x8*)&s_qr[wv * 16 + rsub][kq8];
        const f16x8 a1 = *(const f16x8*)&s_qr[wv * 16 + rsub][32 + kq8];
#pragma unroll
        for (int n = 0; n < 8; n++) {
            f32x4 acc = (f32x4){0.f, 0.f, 0.f, 0.f};
            const f16x8 b0 = *(const f16x8*)&s_ST[n * 16 + rsub][kq8];
            const f16x8 b1 = *(const f16x8*)&s_ST[n * 16 + rsub][32 + kq8];
            acc = __builtin_amdgcn_mfma_f32_16x16x32_f16(a0, b0, acc, 0, 0, 0);
            acc = __builtin_amdgcn_mfma_f32_16x16x32_f16(a1, b1, acc, 0, 0, 0);
            const int dv = n * 16 + rsub;
#pragma unroll
            for (int r = 0; r < 4; r++) s_O2[wv * 16 + r0 + r][dv] = acc[r];
        }
    }
    __syncthreads();
    const int t = tid >> 2, dv0 = (tid & 3) * 32;
    float o[32];
    const u16* op = obuf + ((size_t)bh * LSEQ + c * 64 + t) * DVH + dv0;
#pragma unroll
    for (int j8 = 0; j8 < 32; j8 += 8) {
        const uint4 u = *(const uint4*)(op + j8);
        o[j8 + 0] = bf2f((u16)(u.x & 0xffff)); o[j8 + 1] = bf2f((u16)(u.x >> 16));
        o[j8 + 2] = bf2f((u16)(u.y & 0xffff)); o[j8 + 3] = bf2f((u16)(u.y >> 16));
        o[j8 + 4] = bf2f((u16)(u.z & 0xffff)); o[j8 + 5] = bf2f((u16)(u.z >> 16));
        o[j8 + 6] = bf2f((u16)(u.w & 0xffff)); o[j8 + 7] = bf2f((u16)(u.w >> 16));
    }
#pragma unroll
    for (int j = 0; j < 32; j += 4) {
        const f32x4 sv = *(const f32x4*)&s_O2[t][dv0 + j];
        o[j + 0] += sv[0]; o[j + 1] += sv[1]; o[j + 2] += sv[2]; o[j + 3] += sv[3];
    }
    const float aw = augw[(size_t)bh * LSEQ + c * 64 + t];
    const u16* vp = v + (rowBase + t) * E + h * 128 + dv0;
#pragma unroll
    for (int j8 = 0; j8 < 32; j8 += 8) {
        const uint4 u = *(const uint4*)(vp + j8);
        const float vv[8] = {
            bf2f((u16)(u.x & 0xffff)), bf2f((u16)(u.x >> 16)),
            bf2f((u16)(u.y & 0xffff)), bf2f((u16)(u.y >> 16)),
            bf2f((u16)(u.z & 0xffff)), bf2f((u16)(u.z >> 16)),
            bf2f((u16)(u.w & 0xffff)), bf2f((u16)(u.w >> 16)) };
#pragma unroll
        for (int j = 0; j < 8; j++)
            o[j8 + j] += 1.f / (1.f + __expf(-aw * vv[j]));
    }
    float sum = 0.f;
#pragma unroll
    for (int j = 0; j < 32; j++) sum += o[j];
    sum += __shfl_xor(sum, 1); sum += __shfl_xor(sum, 2);
    const float mu = sum * (1.f / 128.f);
    float sq = 0.f;
#pragma unroll
    for (int j = 0; j < 32; j++) { const float dlt = o[j] - mu; sq = fmaf(dlt, dlt, sq); }
    sq += __shfl_xor(sq, 1); sq += __shfl_xor(sq, 2);
    const float rs = rsqrtf(sq * (1.f / 128.f) + LN_EPS);
    const u16* sp2 = sg + (rowBase + t) * E + h * 128 + dv0;
    u16* ap = a2 + (rowBase + t) * E + h * 128 + dv0;
#pragma unroll
    for (int j8 = 0; j8 < 32; j8 += 8) {
        const uint4 us = *(const uint4*)(sp2 + j8);
        const float sv[8] = {
            bf2f((u16)(us.x & 0xffff)), bf2f((u16)(us.x >> 16)),
            bf2f((u16)(us.y & 0xffff)), bf2f((u16)(us.y >> 16)),
            bf2f((u16)(us.z & 0xffff)), bf2f((u16)(us.z >> 16)),
            bf2f((u16)(us.w & 0xffff)), bf2f((u16)(us.w >> 16)) };
        uint4 u;
        u.x = (u32)f2bf(sv[0] * ((o[j8 + 0] - mu) * rs)) | ((u32)f2bf(sv[1] * ((o[j8 + 1] - mu) * rs)) << 16);
        u.y = (u32)f2bf(sv[2] * ((o[j8 + 2] - mu) * rs)) | ((u32)f2bf(sv[3] * ((o[j8 + 3] - mu) * rs)) << 16);
        u.z = (u32)f2bf(sv[4] * ((o[j8 + 4] - mu) * rs)) | ((u32)f2bf(sv[5] * ((o[j8 + 5] - mu) * rs)) << 16);
        u.w = (u32)f2bf(sv[6] * ((o[j8 + 6] - mu) * rs)) | ((u32)f2bf(sv[7] * ((o[j8 + 7] - mu) * rs)) << 16);
        *(uint4*)(ap + j8) = u;
    }
}

// ----------------------------------------------------------------- launcher
extern "C" void kernel_launch(void* const* d_in, const int* in_sizes, int n_in,
                              void* d_out, int out_size, void* d_ws, size_t ws_size,
                              hipStream_t stream) {
    const float* x      = (const float*)d_in[0];
    const float* conv_w = (const float*)d_in[1];
    const float* wq     = (const float*)d_in[2];
    const float* wkg    = (const float*)d_in[3];
    const float* wv     = (const float*)d_in[4];
    const float* wg     = (const float*)d_in[5];
    const float* bg     = (const float*)d_in[6];
    const float* wout   = (const float*)d_in[7];
    const float* aug    = (const float*)d_in[8];

    char* ws = (char*)d_ws;
    size_t off = 0;
    auto alloc = [&](size_t bytes) -> char* {
        char* p = ws + off;
        off += (bytes + 255) & ~(size_t)255;
        return p;
    };
    u16* xc    = (u16*)alloc((size_t)MROWS * E * 2);
    u16* wcat  = (u16*)alloc((size_t)3072 * E * 2);
    u16* woutT = (u16*)alloc((size_t)E * E * 2);
    u16* qb    = (u16*)alloc((size_t)MROWS * DK * 2);
    u16* kgb   = (u16*)alloc((size_t)MROWS * DK * 2);
    u16* vb    = (u16*)alloc((size_t)MROWS * E * 2);
    u16* sgb   = (u16*)alloc((size_t)MROWS * E * 2);
    u16* qtb   = (u16*)alloc((size_t)MROWS * DK * 2);
    u16* obuf  = (u16*)alloc((size_t)32 * LSEQ * DVH * 2);
    u16* Ssb   = (u16*)alloc((size_t)32 * NCHUNK * DKH * DVH * 2);  // 16.8 MB
    float* Dc  = (float*)alloc((size_t)32 * NCHUNK * DKH * 4);
    float* augw= (float*)alloc((size_t)32 * LSEQ * 4);
    u16* a2    = qb;                 // reuse q+kg region (dead after gla1)
    u16* Sd    = (u16*)d_out;        // bf16 deltas; overwritten by final GEMM

    k_pre<<<5632, 256, 0, stream>>>(x, conv_w, xc, wq, wkg, wv, wg, wout, wcat, woutT);
    k_gemm0<<<1024, 256, 0, stream>>>(xc, wcat, qb, kgb, vb, sgb, bg);
    k_gla1<<<dim3(NCHUNK, 32), 256, 0, stream>>>(qb, kgb, vb, aug, qtb, obuf, Sd, Dc, augw);
    k_gla2<<<1024, 256, 0, stream>>>(Sd, Ssb, Dc);
    k_gla3<<<dim3(NCHUNK, 32), 256, 0, stream>>>(qtb, vb, sgb, obuf, Ssb, augw, a2);
    k_gemm1<<<dim3(32, 8), 512, 0, stream>>>(a2, woutT, (float*)d_out);
}